// Round 15
// baseline (1002.286 us; speedup 1.0000x reference)
//
#include <hip/hip_runtime.h>
#include <math.h>

#define DIM    768
#define BATCH  1024
#define NANS   128000
#define NT128  1000             // 128-answer shortlist tiles
#define NWORDS 4000             // mask bit-words per batch row (128000/32)

typedef short  bf16x8 __attribute__((ext_vector_type(8)));
typedef float  f32x4  __attribute__((ext_vector_type(4)));
typedef unsigned long long u64;

__device__ __forceinline__ short f2bf(float x)
{
    unsigned u = __builtin_bit_cast(unsigned, x);
    u += 0x7fffu + ((u >> 16) & 1u);          // RNE (no NaN inputs here)
    return (short)(u >> 16);
}

__device__ __forceinline__ void gload16(const void* g, void* l)
{
    __builtin_amdgcn_global_load_lds(
        (const __attribute__((address_space(1))) void*)g,
        (__attribute__((address_space(3))) void*)l, 16, 0, 0);
}

// sortable-u32 transform: monotone f32 -> u32 (neg -> ~u, pos -> u|0x80000000)
__device__ __forceinline__ unsigned f2sort(float s)
{
    unsigned u = __builtin_bit_cast(unsigned, s);
    return u ^ ((unsigned)((int)u >> 31) | 0x80000000u);
}

__device__ __forceinline__ unsigned umaxu(unsigned a, unsigned b) { return a > b ? a : b; }
__device__ __forceinline__ unsigned uminu(unsigned a, unsigned b) { return a < b ? a : b; }

// u32-packed top-10: key = (sortable(score) & ~0x7F) | (127 - local_idx).
// Insert = v_max_u32 + v_min_u32 per step (2 VALU) — no cndmask, no cmp.
struct Top10k { unsigned k0,k1,k2,k3,k4,k5,k6,k7,k8,k9; };
__device__ __forceinline__ void t10k_init(Top10k& t)
{ t.k0=t.k1=t.k2=t.k3=t.k4=t.k5=t.k6=t.k7=t.k8=t.k9=0u; }
__device__ __forceinline__ void t10k_ins(Top10k& t, unsigned v)
{
#define TS(K) { unsigned mx = umaxu(v, t.K); v = uminu(v, t.K); t.K = mx; }
    TS(k0) TS(k1) TS(k2) TS(k3) TS(k4) TS(k5) TS(k6) TS(k7) TS(k8) TS(k9)
#undef TS
}

// u64 top-16 for the merge phase: v = (key32<<32) | position  (10M inserts)
struct Top16u { u64 k0,k1,k2,k3,k4,k5,k6,k7,k8,k9,k10,k11,k12,k13,k14,k15; };
__device__ __forceinline__ void t16u_init(Top16u& t)
{
    t.k0=t.k1=t.k2=t.k3=t.k4=t.k5=t.k6=t.k7=0ull;
    t.k8=t.k9=t.k10=t.k11=t.k12=t.k13=t.k14=t.k15=0ull;
}
__device__ __forceinline__ void t16u_ins(Top16u& t, u64 v)
{
#define TS(K) { bool g = v > t.K; u64 mx = g ? v : t.K; v = g ? t.K : v; t.K = mx; }
    TS(k0)  TS(k1)  TS(k2)  TS(k3)  TS(k4)  TS(k5)  TS(k6)  TS(k7)
    TS(k8)  TS(k9)  TS(k10) TS(k11) TS(k12) TS(k13) TS(k14) TS(k15)
#undef TS
}

// ---------------------------------------------------------------------------
// Upstream GEMM: C[M,N] = A[M,K] @ W[N,K]^T (+ bias | += accum)   (fp32)
// W row stride = wstride (for slicing fusion_w into left/right halves).
// ---------------------------------------------------------------------------
__global__ __launch_bounds__(256, 2) void gemm_bias_k(
    const float* __restrict__ A, int lda,
    const float* __restrict__ W, int wstride,
    const float* __restrict__ bias,
    float* __restrict__ C, int ldc, int K, int accum)
{
    __shared__ float as[32][68];
    __shared__ float bs[32][68];
    int m0 = blockIdx.x * 64, n0 = blockIdx.y * 64;
    int tid = threadIdx.x;
    int tm = tid & 15, tn = tid >> 4;
    int sr = tid >> 3, skq = tid & 7;
    float acc[4][4] = {};
    for (int k0 = 0; k0 < K; k0 += 32) {
        __syncthreads();
        #pragma unroll
        for (int p = 0; p < 2; ++p) {
            int r = sr + 32 * p;
            float4 av = *(const float4*)&A[(size_t)(m0 + r) * lda + k0 + skq * 4];
            as[skq*4+0][r] = av.x; as[skq*4+1][r] = av.y;
            as[skq*4+2][r] = av.z; as[skq*4+3][r] = av.w;
            float4 wv = *(const float4*)&W[(size_t)(n0 + r) * wstride + k0 + skq * 4];
            bs[skq*4+0][r] = wv.x; bs[skq*4+1][r] = wv.y;
            bs[skq*4+2][r] = wv.z; bs[skq*4+3][r] = wv.w;
        }
        __syncthreads();
        #pragma unroll 8
        for (int k = 0; k < 32; ++k) {
            float a4[4], b4[4];
            *(float4*)a4 = *(const float4*)&as[k][tm*4];
            *(float4*)b4 = *(const float4*)&bs[k][tn*4];
            #pragma unroll
            for (int i = 0; i < 4; ++i)
                #pragma unroll
                for (int j = 0; j < 4; ++j)
                    acc[i][j] = fmaf(a4[i], b4[j], acc[i][j]);
        }
    }
    if (accum) {
        #pragma unroll
        for (int i = 0; i < 4; ++i) {
            float* cp = &C[(size_t)(m0 + tm*4 + i) * ldc + n0 + tn*4];
            float4 c4 = *(float4*)cp;
            c4.x += acc[i][0]; c4.y += acc[i][1];
            c4.z += acc[i][2]; c4.w += acc[i][3];
            *(float4*)cp = c4;
        }
    } else {
        float4 bv4 = *(const float4*)&bias[n0 + tn*4];
        #pragma unroll
        for (int i = 0; i < 4; ++i) {
            float4 c4;
            c4.x = acc[i][0] + bv4.x; c4.y = acc[i][1] + bv4.y;
            c4.z = acc[i][2] + bv4.z; c4.w = acc[i][3] + bv4.w;
            *(float4*)&C[(size_t)(m0 + tm*4 + i) * ldc + n0 + tn*4] = c4;
        }
    }
}

// ---------------------------------------------------------------------------
__device__ __forceinline__ float block_sum(float v, float* red)
{
    #pragma unroll
    for (int o = 32; o; o >>= 1) v += __shfl_down(v, o);
    if ((threadIdx.x & 63) == 0) red[threadIdx.x >> 6] = v;
    __syncthreads();
    float r = red[0] + red[1] + red[2] + red[3];
    __syncthreads();
    return r;
}

__global__ __launch_bounds__(256) void ln_gelu_k(float* __restrict__ H,
        const float* __restrict__ g, const float* __restrict__ b)
{
    __shared__ float red[4];
    int row = blockIdx.x, tid = threadIdx.x;
    float* hr = H + (size_t)row * DIM;
    float v0 = hr[tid], v1 = hr[tid + 256], v2 = hr[tid + 512];
    float mu = block_sum(v0 + v1 + v2, red) * (1.0f / 768.0f);
    float d0 = v0 - mu, d1 = v1 - mu, d2 = v2 - mu;
    float var = block_sum(d0*d0 + d1*d1 + d2*d2, red) * (1.0f / 768.0f);
    float rinv = 1.0f / sqrtf(var + 1e-5f);
    #pragma unroll
    for (int q = 0; q < 3; ++q) {
        int d = tid + 256 * q;
        float dd = (q == 0 ? d0 : (q == 1 ? d1 : d2));
        float y = dd * rinv * g[d] + b[d];
        hr[d] = 0.5f * y * (1.0f + erff(y * 0.70710678118654752f));
    }
}

__global__ __launch_bounds__(256) void l2norm_bf_k(float* __restrict__ P,
        short* __restrict__ Pb)
{
    __shared__ float red[4];
    int row = blockIdx.x, tid = threadIdx.x;
    float* pr = P + (size_t)row * DIM;
    short* pb = Pb + (size_t)row * DIM;
    float v0 = pr[tid], v1 = pr[tid + 256], v2 = pr[tid + 512];
    float ss = block_sum(v0*v0 + v1*v1 + v2*v2, red);
    float inv = 1.0f / fmaxf(sqrtf(ss), 1e-12f);
    v0 *= inv; v1 *= inv; v2 *= inv;
    pr[tid] = v0; pr[tid + 256] = v1; pr[tid + 512] = v2;
    pb[tid] = f2bf(v0); pb[tid + 256] = f2bf(v1); pb[tid + 512] = f2bf(v2);
}

// ---------------------------------------------------------------------------
// prep_ans: fp64 row norm -> inv64[row]; unit-normalized bf16 rows into AB.
// ---------------------------------------------------------------------------
__global__ __launch_bounds__(256) void prep_ans_k(
    const float* __restrict__ ANS, int row0, int nrows,
    double* __restrict__ inv64, short* __restrict__ AB)
{
    int r = blockIdx.x * 4 + (threadIdx.x >> 6);
    if (r >= nrows) return;
    int row = row0 + r;
    int lane = threadIdx.x & 63;
    const float4* a4 = (const float4*)(ANS + (size_t)row * DIM);
    float4 x0 = a4[lane], x1 = a4[lane + 64], x2 = a4[lane + 128];
    double ss = (double)x0.x*x0.x + (double)x0.y*x0.y + (double)x0.z*x0.z + (double)x0.w*x0.w
              + (double)x1.x*x1.x + (double)x1.y*x1.y + (double)x1.z*x1.z + (double)x1.w*x1.w
              + (double)x2.x*x2.x + (double)x2.y*x2.y + (double)x2.z*x2.z + (double)x2.w*x2.w;
    #pragma unroll
    for (int o = 32; o; o >>= 1) ss += __shfl_xor(ss, o);
    double inv = 1.0 / fmax(sqrt(ss), 1e-12);
    if (lane == 0) inv64[row] = inv;
    float invf = (float)inv;
    short* ob = AB + (size_t)r * DIM;
    ushort4 o0, o1, o2;
    o0.x = (unsigned short)f2bf(x0.x*invf); o0.y = (unsigned short)f2bf(x0.y*invf);
    o0.z = (unsigned short)f2bf(x0.z*invf); o0.w = (unsigned short)f2bf(x0.w*invf);
    o1.x = (unsigned short)f2bf(x1.x*invf); o1.y = (unsigned short)f2bf(x1.y*invf);
    o1.z = (unsigned short)f2bf(x1.z*invf); o1.w = (unsigned short)f2bf(x1.w*invf);
    o2.x = (unsigned short)f2bf(x2.x*invf); o2.y = (unsigned short)f2bf(x2.y*invf);
    o2.z = (unsigned short)f2bf(x2.z*invf); o2.w = (unsigned short)f2bf(x2.w*invf);
    *(ushort4*)&ob[lane * 4]           = o0;
    *(ushort4*)&ob[(lane + 64) * 4]    = o1;
    *(ushort4*)&ob[(lane + 128) * 4]   = o2;
}

// ---------------------------------------------------------------------------
// prep_maskT: float mask [1024][128000] -> TRANSPOSED bits [4000][1024]
// grid (4, 200): 800 blocks, 20 words each -> HBM-saturating occupancy.
// ---------------------------------------------------------------------------
__global__ __launch_bounds__(256, 4) void prep_maskT_k(
    const float* __restrict__ mask, unsigned* __restrict__ bitsT)
{
    int r = blockIdx.x * 256 + threadIdx.x;
    int w0 = blockIdx.y * 20;
    const float* mr = mask + (size_t)r * NANS;
    for (int w = w0; w < w0 + 20; ++w) {
        const float4* p = (const float4*)(mr + w * 32);
        unsigned b = 0;
        #pragma unroll
        for (int q = 0; q < 8; ++q) {
            float4 v = p[q];
            b |= ((unsigned)(v.x != 0.f)) << (q*4+0);
            b |= ((unsigned)(v.y != 0.f)) << (q*4+1);
            b |= ((unsigned)(v.z != 0.f)) << (q*4+2);
            b |= ((unsigned)(v.w != 0.f)) << (q*4+3);
        }
        bitsT[(size_t)w * BATCH + r] = b;
    }
}

// ---------------------------------------------------------------------------
// gemmsel_k: fused MFMA GEMM (2-phase dbuf staging) + mask + per-(row,tile)
// top-10 via u32-packed max/min chains + shfl-pair bitonic merge.
// Epilogue uses TRANSPOSED sclT[col][68] so dump/scan are ds_*_b128.
// 256 thr / 4 waves; tile 128 answers x 128 batch; BK=32; 24 K-steps.
// ---------------------------------------------------------------------------
__global__ __launch_bounds__(256, 2) void gemmsel_k(
    const short* __restrict__ Pb,       // [1024][768] unit-norm bf16
    const short* __restrict__ AB,       // chunk rows, unit-norm bf16
    const unsigned* __restrict__ bitsT, // [4000][1024]
    unsigned* __restrict__ ck,          // [1024][1000*10] packed u32 keys
    int t128_0, int nt128)
{
    __shared__ __align__(16) char smem[34816];
    // staging: 2 bufs x (A [128][32] + B [128][32]) shorts = 32768 B
    float* scl = (float*)smem;                  // epilogue reuse: [128][68] f32

    int bid = blockIdx.x;
    int v = (bid & 7) * nt128 + (bid >> 3);
    int at = v >> 3, bt = v & 7;
    int gt = t128_0 + at;                       // global 128-tile id
    int a0l = at * 128, b0 = bt * 128;

    int tid = threadIdx.x;
    int lane = tid & 63, wid = tid >> 6;
    int wm = wid & 1, wn = wid >> 1;            // 2x2 wave grid of 64x64
    int lr = lane & 15, lg = lane >> 4;

    const char* gA0 = (const char*)(AB + (size_t)(a0l + (tid >> 2)) * DIM + (tid & 3) * 8);
    const char* gA1 = (const char*)(AB + (size_t)(a0l + 64 + (tid >> 2)) * DIM + (tid & 3) * 8);
    const char* gB0 = (const char*)(Pb + (size_t)(b0 + (tid >> 2)) * DIM + (tid & 3) * 8);
    const char* gB1 = (const char*)(Pb + (size_t)(b0 + 64 + (tid >> 2)) * DIM + (tid & 3) * 8);

    f32x4 acc[4][4];
    #pragma unroll
    for (int i = 0; i < 4; ++i)
        #pragma unroll
        for (int j = 0; j < 4; ++j)
            acc[i][j] = (f32x4){0.f, 0.f, 0.f, 0.f};

    // prologue: stage kt=0 into buf 0
    {
        char* la = smem + tid * 16;
        gload16(gA0, la);
        gload16(gA1, la + 4096);
        gload16(gB0, la + 16384);
        gload16(gB1, la + 20480);
    }
    __syncthreads();

    int buf = 0;
    for (int kt = 0; kt < 24; ++kt) {
        if (kt < 23) {                          // stage next tile into buf^1
            int kb = (kt + 1) * 64;
            char* la = smem + (buf ^ 1) * 8192 + tid * 16;
            gload16(gA0 + kb, la);
            gload16(gA1 + kb, la + 4096);
            gload16(gB0 + kb, la + 16384);
            gload16(gB1 + kb, la + 20480);
        }
        const short* a_sh = (const short*)(smem + buf * 8192);
        const short* b_sh = (const short*)(smem + 16384 + buf * 8192);
        bf16x8 af[4], bg[4];
        #pragma unroll
        for (int mt = 0; mt < 4; ++mt)
            af[mt] = *(const bf16x8*)(a_sh + (wm*64 + mt*16 + lr) * 32 + lg*8);
        #pragma unroll
        for (int nt = 0; nt < 4; ++nt)
            bg[nt] = *(const bf16x8*)(b_sh + (wn*64 + nt*16 + lr) * 32 + lg*8);
        #pragma unroll
        for (int mt = 0; mt < 4; ++mt)
            #pragma unroll
            for (int nt = 0; nt < 4; ++nt)
                acc[mt][nt] = __builtin_amdgcn_mfma_f32_16x16x32_bf16(
                    af[mt], bg[nt], acc[mt][nt], 0, 0, 0);
        __syncthreads();                        // drains next-tile loads too
        buf ^= 1;
    }

    // ---- epilogue: bitmask + per-column top-10, u32 keys in named regs ----
    Top10k tp;
    t10k_init(tp);
    int col = tid >> 1, qt = tid & 1;           // pair lanes share a column
    int qoff = qt * 32;

    for (int c = 0; c < 2; ++c) {               // 64-answer chunks
        __syncthreads();
        if (wm == c) {                          // transposed dump: 16x b128
            #pragma unroll
            for (int nt = 0; nt < 4; ++nt) {
                int lcol = wn * 64 + nt * 16 + lr;
                #pragma unroll
                for (int mt = 0; mt < 4; ++mt) {
                    int lrow = mt * 16 + lg * 4;
                    *(f32x4*)&scl[lcol * 68 + lrow] = acc[mt][nt];
                }
            }
        }
        __syncthreads();
        unsigned wv = bitsT[(size_t)(gt * 4 + c * 2 + qt) * BATCH + b0 + col];
        unsigned lobc = (unsigned)(127 - c * 64 - qoff);   // 127 - local base
        #pragma unroll
        for (int i4 = 0; i4 < 8; ++i4) {        // 8x b128 scan per chunk
            f32x4 s4 = *(const f32x4*)&scl[col * 68 + qoff + i4 * 4];
            #pragma unroll
            for (int j = 0; j < 4; ++j) {
                int i = i4 * 4 + j;
                float sc = ((wv >> i) & 1u) ? s4[j] : 0.0f;
                unsigned key = (f2sort(sc) & 0xFFFFFF80u) | (lobc - (unsigned)i);
                t10k_ins(tp, key);
            }
        }
    }

    // pair merge: top-10 of two sorted-desc 10-lists = {max(A[i], B[9-i])}
    unsigned q0 = __shfl_xor(tp.k0, 1), q1 = __shfl_xor(tp.k1, 1);
    unsigned q2 = __shfl_xor(tp.k2, 1), q3 = __shfl_xor(tp.k3, 1);
    unsigned q4 = __shfl_xor(tp.k4, 1), q5 = __shfl_xor(tp.k5, 1);
    unsigned q6 = __shfl_xor(tp.k6, 1), q7 = __shfl_xor(tp.k7, 1);
    unsigned q8 = __shfl_xor(tp.k8, 1), q9 = __shfl_xor(tp.k9, 1);
    if (qt == 0) {
        unsigned* dst = ck + (size_t)(b0 + col) * (NT128 * 10) + (size_t)gt * 10;
        dst[0] = umaxu(tp.k0, q9);
        dst[1] = umaxu(tp.k1, q8);
        dst[2] = umaxu(tp.k2, q7);
        dst[3] = umaxu(tp.k3, q6);
        dst[4] = umaxu(tp.k4, q5);
        dst[5] = umaxu(tp.k5, q4);
        dst[6] = umaxu(tp.k6, q3);
        dst[7] = umaxu(tp.k7, q2);
        dst[8] = umaxu(tp.k8, q1);
        dst[9] = umaxu(tp.k9, q0);
    }
}

// ---------------------------------------------------------------------------
// merge_rescore5: stream row's 10000 u32 keys (coalesced) -> per-thread
// top-16 of (key<<32)|pos -> LDS 4096 -> global top-16 -> fp64 rescore ->
// final top-10 + gather.  idx = (pos/10)*128 + 127 - (key & 0x7F).
// ---------------------------------------------------------------------------
__global__ __launch_bounds__(256) void merge_rescore5_k(
    const unsigned* __restrict__ ck,
    const float* __restrict__ P, const float* __restrict__ ANS,
    const double* __restrict__ invn64, const float* __restrict__ mask,
    float* __restrict__ out)
{
    __shared__ u64    lk[4096];
    __shared__ u64    rrk[4];
    __shared__ int    rrp[4];
    __shared__ int    topi_s[16];
    __shared__ double tops_s[16];
    __shared__ int    fin_s[10];
    int row = blockIdx.x, tid = threadIdx.x;

    Top16u t;
    t16u_init(t);
    const unsigned* ckr = ck + (size_t)row * (NT128 * 10);
    for (int j = tid; j < NT128 * 10; j += 256)
        t16u_ins(t, ((u64)ckr[j] << 32) | (unsigned)j);
    {
        int o = tid * 16;
        lk[o+0]=t.k0;  lk[o+1]=t.k1;  lk[o+2]=t.k2;  lk[o+3]=t.k3;
        lk[o+4]=t.k4;  lk[o+5]=t.k5;  lk[o+6]=t.k6;  lk[o+7]=t.k7;
        lk[o+8]=t.k8;  lk[o+9]=t.k9;  lk[o+10]=t.k10; lk[o+11]=t.k11;
        lk[o+12]=t.k12; lk[o+13]=t.k13; lk[o+14]=t.k14; lk[o+15]=t.k15;
    }
    __syncthreads();

    for (int it = 0; it < 16; ++it) {
        u64 bk = 0; int bp = -1;
        for (int j = tid; j < 4096; j += 256) {
            u64 k = lk[j];
            if (k > bk) { bk = k; bp = j; }
        }
        #pragma unroll
        for (int o = 32; o; o >>= 1) {
            u64 ok = __shfl_down(bk, o);
            int op = __shfl_down(bp, o);
            if (ok > bk) { bk = ok; bp = op; }
        }
        if ((tid & 63) == 0) { rrk[tid >> 6] = bk; rrp[tid >> 6] = bp; }
        __syncthreads();
        if (tid == 0) {
            for (int w = 1; w < 4; ++w)
                if (rrk[w] > bk) { bk = rrk[w]; bp = rrp[w]; }
            unsigned key = (unsigned)(bk >> 32);
            int pos = (int)(bk & 0xffffffffull);
            topi_s[it] = (pos / 10) * 128 + 127 - (int)(key & 0x7Fu);
            lk[bp] = 0;
        }
        __syncthreads();
    }

    // fp64 rescore: 16 threads per candidate
    int c = tid >> 4, part = tid & 15;
    int aidx = topi_s[c];
    const float4* p4 = (const float4*)(P + (size_t)row * DIM);
    const float4* a4 = (const float4*)(ANS + (size_t)aidx * DIM);
    double sum = 0.0;
    #pragma unroll
    for (int i = 0; i < 12; ++i) {
        float4 pv = p4[part * 12 + i];
        float4 av = a4[part * 12 + i];
        sum += (double)pv.x * av.x + (double)pv.y * av.y
             + (double)pv.z * av.z + (double)pv.w * av.w;
    }
    #pragma unroll
    for (int o = 8; o; o >>= 1) sum += __shfl_down(sum, o, 16);
    if (part == 0) {
        float m = mask[(size_t)row * NANS + aidx];
        tops_s[c] = sum * invn64[aidx] * (double)m;
    }
    __syncthreads();

    if (tid == 0) {
        unsigned used = 0;
        for (int k = 0; k < 10; ++k) {
            int bj = -1;
            for (int j = 0; j < 16; ++j) {
                if (used & (1u << j)) continue;
                if (bj < 0 || tops_s[j] > tops_s[bj] ||
                    (tops_s[j] == tops_s[bj] && topi_s[j] < topi_s[bj])) bj = j;
            }
            used |= 1u << bj;
            out[(size_t)row * 10 + k] = (float)tops_s[bj];
            out[10240 + (size_t)row * 10 + k] = (float)topi_s[bj];
            fin_s[k] = topi_s[bj];
        }
    }
    __syncthreads();

    for (int k = 0; k < 10; ++k) {
        int id = fin_s[k];
        const float* arow = ANS + (size_t)id * DIM;
        float* orow = out + 20480 + ((size_t)(row * 10 + k)) * DIM;
        for (int d = tid; d < DIM; d += 256) orow[d] = arow[d];
    }
}

// ---------------------------------------------------------------------------
extern "C" void kernel_launch(void* const* d_in, const int* in_sizes, int n_in,
                              void* d_out, int out_size, void* d_ws, size_t ws_size,
                              hipStream_t stream)
{
    (void)in_sizes; (void)n_in; (void)out_size;
    const float* visual = (const float*)d_in[0];
    const float* mask   = (const float*)d_in[2];
    const float* ans    = (const float*)d_in[3];
    const float* wv = (const float*)d_in[8];
    const float* bv = (const float*)d_in[9];
    const float* wo = (const float*)d_in[10];
    const float* bo = (const float*)d_in[11];
    const float* fw = (const float*)d_in[12];
    const float* fb = (const float*)d_in[13];
    const float* lg = (const float*)d_in[14];
    const float* lb = (const float*)d_in[15];
    const float* sw = (const float*)d_in[16];
    const float* sb = (const float*)d_in[17];
    float* out = (float*)d_out;

    // ---- workspace: persistent first; transient upstream + AB share tail ----
    char* w = (char*)d_ws;
    float*    P      = (float*)w;    w += (size_t)BATCH * DIM * 4;          // 3.1 MB
    short*    Pb     = (short*)w;    w += (size_t)BATCH * DIM * 2;          // 1.6 MB
    double*   invn64 = (double*)w;   w += (size_t)NANS * 8;                 // 1.0 MB
    unsigned* ck     = (unsigned*)w; w += (size_t)BATCH * NT128 * 10 * 4;   // 41 MB
    unsigned* bitsT  = (unsigned*)w; w += (size_t)NWORDS * BATCH * 4;       // 16.4 MB
    char*     tail   = w;
    float*    v      = (float*)tail;                    // upstream transients
    float*    att    = v + (size_t)BATCH * DIM;
    float*    h      = att + (size_t)BATCH * DIM;
    short*    AB     = (short*)tail;  // reuses upstream transients after death

    size_t ab_t = (size_t)128 * DIM * 2;        // 196608 B per 128-tile
    size_t used = (size_t)(tail - (char*)d_ws);
    size_t avail = (ws_size > used) ? (ws_size - used) : ab_t;
    int CT = (int)(avail / ab_t);               // tiles per chunk
    if (CT < 1) CT = 1;
    if (CT > NT128) CT = NT128;
    int nch = (NT128 + CT - 1) / CT;

    gemm_bias_k<<<dim3(16, 12), 256, 0, stream>>>(visual, DIM, wv, DIM, bv, v, DIM, DIM, 0);
    gemm_bias_k<<<dim3(16, 12), 256, 0, stream>>>(v, DIM, wo, DIM, bo, att, DIM, DIM, 0);
    gemm_bias_k<<<dim3(16, 12), 256, 0, stream>>>(visual, DIM, fw, 2*DIM, fb, h, DIM, DIM, 0);
    gemm_bias_k<<<dim3(16, 12), 256, 0, stream>>>(att, DIM, fw + DIM, 2*DIM, nullptr, h, DIM, DIM, 1);
    ln_gelu_k<<<BATCH, 256, 0, stream>>>(h, lg, lb);
    gemm_bias_k<<<dim3(16, 12), 256, 0, stream>>>(h, DIM, sw, DIM, sb, P, DIM, DIM, 0);
    l2norm_bf_k<<<BATCH, 256, 0, stream>>>(P, Pb);
    prep_maskT_k<<<dim3(4, 200), 256, 0, stream>>>(mask, bitsT);
    // ---- upstream transients dead from here; AB reuses the tail ----

    for (int ch = 0; ch < nch; ++ch) {
        int t0 = ch * CT;
        int n = NT128 - t0; if (n > CT) n = CT;
        int nrows = n * 128;
        prep_ans_k<<<(nrows + 3) / 4, 256, 0, stream>>>(ans, t0 * 128, nrows,
                                                        invn64, AB);
        gemmsel_k<<<n * 8, 256, 0, stream>>>(Pb, AB, bitsT, ck, t0, n);
    }

    merge_rescore5_k<<<BATCH, 256, 0, stream>>>(ck, P, ans, invn64, mask, out);
}

// Round 17
// 996.175 us; speedup vs baseline: 1.0061x; 1.0061x over previous
//
#include <hip/hip_runtime.h>
#include <math.h>

#define DIM    768
#define BATCH  1024
#define NANS   128000
#define NT128  1000             // 128-answer shortlist tiles
#define NWORDS 4000             // mask bit-words per batch row (128000/32)

typedef short  bf16x8 __attribute__((ext_vector_type(8)));
typedef float  f32x4  __attribute__((ext_vector_type(4)));
typedef unsigned long long u64;

__device__ __forceinline__ short f2bf(float x)
{
    unsigned u = __builtin_bit_cast(unsigned, x);
    u += 0x7fffu + ((u >> 16) & 1u);          // RNE (no NaN inputs here)
    return (short)(u >> 16);
}

__device__ __forceinline__ void gload16(const void* g, void* l)
{
    __builtin_amdgcn_global_load_lds(
        (const __attribute__((address_space(1))) void*)g,
        (__attribute__((address_space(3))) void*)l, 16, 0, 0);
}

// sortable-u32 transform: monotone f32 -> u32 (neg -> ~u, pos -> u|0x80000000)
__device__ __forceinline__ unsigned f2sort(float s)
{
    unsigned u = __builtin_bit_cast(unsigned, s);
    return u ^ ((unsigned)((int)u >> 31) | 0x80000000u);
}

__device__ __forceinline__ unsigned umaxu(unsigned a, unsigned b) { return a > b ? a : b; }
__device__ __forceinline__ unsigned uminu(unsigned a, unsigned b) { return a < b ? a : b; }

// u32-packed top-10: key = (sortable(score) & ~0x7F) | (127 - local_idx).
// Insert = v_max_u32 + v_min_u32 per step (2 VALU) — no cndmask, no cmp.
struct Top10k { unsigned k0,k1,k2,k3,k4,k5,k6,k7,k8,k9; };
__device__ __forceinline__ void t10k_init(Top10k& t)
{ t.k0=t.k1=t.k2=t.k3=t.k4=t.k5=t.k6=t.k7=t.k8=t.k9=0u; }
__device__ __forceinline__ void t10k_ins(Top10k& t, unsigned v)
{
#define TS(K) { unsigned mx = umaxu(v, t.K); v = uminu(v, t.K); t.K = mx; }
    TS(k0) TS(k1) TS(k2) TS(k3) TS(k4) TS(k5) TS(k6) TS(k7) TS(k8) TS(k9)
#undef TS
}

// u64 top-16 for the merge phase: v = (key32<<32) | position  (10M inserts)
struct Top16u { u64 k0,k1,k2,k3,k4,k5,k6,k7,k8,k9,k10,k11,k12,k13,k14,k15; };
__device__ __forceinline__ void t16u_init(Top16u& t)
{
    t.k0=t.k1=t.k2=t.k3=t.k4=t.k5=t.k6=t.k7=0ull;
    t.k8=t.k9=t.k10=t.k11=t.k12=t.k13=t.k14=t.k15=0ull;
}
__device__ __forceinline__ void t16u_ins(Top16u& t, u64 v)
{
#define TS(K) { bool g = v > t.K; u64 mx = g ? v : t.K; v = g ? t.K : v; t.K = mx; }
    TS(k0)  TS(k1)  TS(k2)  TS(k3)  TS(k4)  TS(k5)  TS(k6)  TS(k7)
    TS(k8)  TS(k9)  TS(k10) TS(k11) TS(k12) TS(k13) TS(k14) TS(k15)
#undef TS
}

// ---------------------------------------------------------------------------
// Upstream GEMM: C[M,N] = A[M,K] @ W[N,K]^T + bias   (fp32)
// ---------------------------------------------------------------------------
__global__ __launch_bounds__(256, 2) void gemm_bias_k(
    const float* __restrict__ A, int lda,
    const float* __restrict__ W,
    const float* __restrict__ bias,
    float* __restrict__ C, int ldc, int K)
{
    __shared__ float as[32][68];
    __shared__ float bs[32][68];
    int m0 = blockIdx.x * 64, n0 = blockIdx.y * 64;
    int tid = threadIdx.x;
    int tm = tid & 15, tn = tid >> 4;
    int sr = tid >> 3, skq = tid & 7;
    float acc[4][4] = {};
    for (int k0 = 0; k0 < K; k0 += 32) {
        __syncthreads();
        #pragma unroll
        for (int p = 0; p < 2; ++p) {
            int r = sr + 32 * p;
            float4 av = *(const float4*)&A[(size_t)(m0 + r) * lda + k0 + skq * 4];
            as[skq*4+0][r] = av.x; as[skq*4+1][r] = av.y;
            as[skq*4+2][r] = av.z; as[skq*4+3][r] = av.w;
            float4 wv = *(const float4*)&W[(size_t)(n0 + r) * K + k0 + skq * 4];
            bs[skq*4+0][r] = wv.x; bs[skq*4+1][r] = wv.y;
            bs[skq*4+2][r] = wv.z; bs[skq*4+3][r] = wv.w;
        }
        __syncthreads();
        #pragma unroll 8
        for (int k = 0; k < 32; ++k) {
            float a4[4], b4[4];
            *(float4*)a4 = *(const float4*)&as[k][tm*4];
            *(float4*)b4 = *(const float4*)&bs[k][tn*4];
            #pragma unroll
            for (int i = 0; i < 4; ++i)
                #pragma unroll
                for (int j = 0; j < 4; ++j)
                    acc[i][j] = fmaf(a4[i], b4[j], acc[i][j]);
        }
    }
    float4 bv4 = *(const float4*)&bias[n0 + tn*4];
    #pragma unroll
    for (int i = 0; i < 4; ++i) {
        float4 c4;
        c4.x = acc[i][0] + bv4.x; c4.y = acc[i][1] + bv4.y;
        c4.z = acc[i][2] + bv4.z; c4.w = acc[i][3] + bv4.w;
        *(float4*)&C[(size_t)(m0 + tm*4 + i) * ldc + n0 + tn*4] = c4;
    }
}

// ---------------------------------------------------------------------------
__global__ void copy_visual_k(const float* __restrict__ src, float* __restrict__ dst)
{
    int idx = blockIdx.x * 256 + threadIdx.x;          // float4 index
    const int total = BATCH * (DIM / 4);
    for (; idx < total; idx += 512 * 256) {
        int b = idx / (DIM / 4), c = idx % (DIM / 4);
        ((float4*)dst)[(size_t)b * (1536 / 4) + c] = ((const float4*)src)[idx];
    }
}

// ---------------------------------------------------------------------------
__device__ __forceinline__ float block_sum(float v, float* red)
{
    #pragma unroll
    for (int o = 32; o; o >>= 1) v += __shfl_down(v, o);
    if ((threadIdx.x & 63) == 0) red[threadIdx.x >> 6] = v;
    __syncthreads();
    float r = red[0] + red[1] + red[2] + red[3];
    __syncthreads();
    return r;
}

__global__ __launch_bounds__(256) void ln_gelu_k(float* __restrict__ H,
        const float* __restrict__ g, const float* __restrict__ b)
{
    __shared__ float red[4];
    int row = blockIdx.x, tid = threadIdx.x;
    float* hr = H + (size_t)row * DIM;
    float v0 = hr[tid], v1 = hr[tid + 256], v2 = hr[tid + 512];
    float mu = block_sum(v0 + v1 + v2, red) * (1.0f / 768.0f);
    float d0 = v0 - mu, d1 = v1 - mu, d2 = v2 - mu;
    float var = block_sum(d0*d0 + d1*d1 + d2*d2, red) * (1.0f / 768.0f);
    float rinv = 1.0f / sqrtf(var + 1e-5f);
    #pragma unroll
    for (int q = 0; q < 3; ++q) {
        int d = tid + 256 * q;
        float dd = (q == 0 ? d0 : (q == 1 ? d1 : d2));
        float y = dd * rinv * g[d] + b[d];
        hr[d] = 0.5f * y * (1.0f + erff(y * 0.70710678118654752f));
    }
}

__global__ __launch_bounds__(256) void l2norm_bf_k(float* __restrict__ P,
        short* __restrict__ Pb)
{
    __shared__ float red[4];
    int row = blockIdx.x, tid = threadIdx.x;
    float* pr = P + (size_t)row * DIM;
    short* pb = Pb + (size_t)row * DIM;
    float v0 = pr[tid], v1 = pr[tid + 256], v2 = pr[tid + 512];
    float ss = block_sum(v0*v0 + v1*v1 + v2*v2, red);
    float inv = 1.0f / fmaxf(sqrtf(ss), 1e-12f);
    v0 *= inv; v1 *= inv; v2 *= inv;
    pr[tid] = v0; pr[tid + 256] = v1; pr[tid + 512] = v2;
    pb[tid] = f2bf(v0); pb[tid + 256] = f2bf(v1); pb[tid + 512] = f2bf(v2);
}

// ---------------------------------------------------------------------------
// prep_ans: fp64 row norm -> inv64[row]; unit-normalized bf16 rows into AB.
// ---------------------------------------------------------------------------
__global__ __launch_bounds__(256) void prep_ans_k(
    const float* __restrict__ ANS, int row0, int nrows,
    double* __restrict__ inv64, short* __restrict__ AB)
{
    int r = blockIdx.x * 4 + (threadIdx.x >> 6);
    if (r >= nrows) return;
    int row = row0 + r;
    int lane = threadIdx.x & 63;
    const float4* a4 = (const float4*)(ANS + (size_t)row * DIM);
    float4 x0 = a4[lane], x1 = a4[lane + 64], x2 = a4[lane + 128];
    double ss = (double)x0.x*x0.x + (double)x0.y*x0.y + (double)x0.z*x0.z + (double)x0.w*x0.w
              + (double)x1.x*x1.x + (double)x1.y*x1.y + (double)x1.z*x1.z + (double)x1.w*x1.w
              + (double)x2.x*x2.x + (double)x2.y*x2.y + (double)x2.z*x2.z + (double)x2.w*x2.w;
    #pragma unroll
    for (int o = 32; o; o >>= 1) ss += __shfl_xor(ss, o);
    double inv = 1.0 / fmax(sqrt(ss), 1e-12);
    if (lane == 0) inv64[row] = inv;
    float invf = (float)inv;
    short* ob = AB + (size_t)r * DIM;
    ushort4 o0, o1, o2;
    o0.x = (unsigned short)f2bf(x0.x*invf); o0.y = (unsigned short)f2bf(x0.y*invf);
    o0.z = (unsigned short)f2bf(x0.z*invf); o0.w = (unsigned short)f2bf(x0.w*invf);
    o1.x = (unsigned short)f2bf(x1.x*invf); o1.y = (unsigned short)f2bf(x1.y*invf);
    o1.z = (unsigned short)f2bf(x1.z*invf); o1.w = (unsigned short)f2bf(x1.w*invf);
    o2.x = (unsigned short)f2bf(x2.x*invf); o2.y = (unsigned short)f2bf(x2.y*invf);
    o2.z = (unsigned short)f2bf(x2.z*invf); o2.w = (unsigned short)f2bf(x2.w*invf);
    *(ushort4*)&ob[lane * 4]           = o0;
    *(ushort4*)&ob[(lane + 64) * 4]    = o1;
    *(ushort4*)&ob[(lane + 128) * 4]   = o2;
}

// ---------------------------------------------------------------------------
// prep_maskT: float mask [1024][128000] -> TRANSPOSED bits [4000][1024]
// grid (4, 200): 800 blocks, 20 words each (R15-validated HBM saturation).
// ---------------------------------------------------------------------------
__global__ __launch_bounds__(256, 4) void prep_maskT_k(
    const float* __restrict__ mask, unsigned* __restrict__ bitsT)
{
    int r = blockIdx.x * 256 + threadIdx.x;
    int w0 = blockIdx.y * 20;
    const float* mr = mask + (size_t)r * NANS;
    for (int w = w0; w < w0 + 20; ++w) {
        const float4* p = (const float4*)(mr + w * 32);
        unsigned b = 0;
        #pragma unroll
        for (int q = 0; q < 8; ++q) {
            float4 v = p[q];
            b |= ((unsigned)(v.x != 0.f)) << (q*4+0);
            b |= ((unsigned)(v.y != 0.f)) << (q*4+1);
            b |= ((unsigned)(v.z != 0.f)) << (q*4+2);
            b |= ((unsigned)(v.w != 0.f)) << (q*4+3);
        }
        bitsT[(size_t)w * BATCH + r] = b;
    }
}

// ---------------------------------------------------------------------------
// gemmsel_k: fused MFMA GEMM (2-phase dbuf staging) + mask + per-(row,tile)
// top-10 via u32-packed max/min chains + shfl-pair bitonic merge.
// 256 thr / 4 waves; tile 128 answers x 128 batch; BK=32; 24 K-steps.
// ---------------------------------------------------------------------------
__global__ __launch_bounds__(256, 2) void gemmsel_k(
    const short* __restrict__ Pb,       // [1024][768] unit-norm bf16
    const short* __restrict__ AB,       // chunk rows, unit-norm bf16
    const unsigned* __restrict__ bitsT, // [4000][1024]
    unsigned* __restrict__ ck,          // [1024][1000*10] packed u32 keys
    int t128_0, int nt128)
{
    __shared__ __align__(16) char smem[33792];
    // staging: 2 bufs x (A [128][32] + B [128][32]) shorts
    float* scl = (float*)smem;                  // epilogue reuse: [64][132]

    int bid = blockIdx.x;
    int v = (bid & 7) * nt128 + (bid >> 3);
    int at = v >> 3, bt = v & 7;
    int gt = t128_0 + at;                       // global 128-tile id
    int a0l = at * 128, b0 = bt * 128;

    int tid = threadIdx.x;
    int lane = tid & 63, wid = tid >> 6;
    int wm = wid & 1, wn = wid >> 1;            // 2x2 wave grid of 64x64
    int lr = lane & 15, lg = lane >> 4;

    const char* gA0 = (const char*)(AB + (size_t)(a0l + (tid >> 2)) * DIM + (tid & 3) * 8);
    const char* gA1 = (const char*)(AB + (size_t)(a0l + 64 + (tid >> 2)) * DIM + (tid & 3) * 8);
    const char* gB0 = (const char*)(Pb + (size_t)(b0 + (tid >> 2)) * DIM + (tid & 3) * 8);
    const char* gB1 = (const char*)(Pb + (size_t)(b0 + 64 + (tid >> 2)) * DIM + (tid & 3) * 8);

    f32x4 acc[4][4];
    #pragma unroll
    for (int i = 0; i < 4; ++i)
        #pragma unroll
        for (int j = 0; j < 4; ++j)
            acc[i][j] = (f32x4){0.f, 0.f, 0.f, 0.f};

    // prologue: stage kt=0 into buf 0
    {
        char* la = smem + tid * 16;
        gload16(gA0, la);
        gload16(gA1, la + 4096);
        gload16(gB0, la + 16384);
        gload16(gB1, la + 20480);
    }
    __syncthreads();

    int buf = 0;
    for (int kt = 0; kt < 24; ++kt) {
        if (kt < 23) {                          // stage next tile into buf^1
            int kb = (kt + 1) * 64;
            char* la = smem + (buf ^ 1) * 8192 + tid * 16;
            gload16(gA0 + kb, la);
            gload16(gA1 + kb, la + 4096);
            gload16(gB0 + kb, la + 16384);
            gload16(gB1 + kb, la + 20480);
        }
        const short* a_sh = (const short*)(smem + buf * 8192);
        const short* b_sh = (const short*)(smem + 16384 + buf * 8192);
        bf16x8 af[4], bg[4];
        #pragma unroll
        for (int mt = 0; mt < 4; ++mt)
            af[mt] = *(const bf16x8*)(a_sh + (wm*64 + mt*16 + lr) * 32 + lg*8);
        #pragma unroll
        for (int nt = 0; nt < 4; ++nt)
            bg[nt] = *(const bf16x8*)(b_sh + (wn*64 + nt*16 + lr) * 32 + lg*8);
        #pragma unroll
        for (int mt = 0; mt < 4; ++mt)
            #pragma unroll
            for (int nt = 0; nt < 4; ++nt)
                acc[mt][nt] = __builtin_amdgcn_mfma_f32_16x16x32_bf16(
                    af[mt], bg[nt], acc[mt][nt], 0, 0, 0);
        __syncthreads();                        // drains next-tile loads too
        buf ^= 1;
    }

    // ---- epilogue: bitmask + per-column top-10, u32 keys in named regs ----
    Top10k tp;
    t10k_init(tp);
    int col = tid >> 1, qt = tid & 1;           // pair lanes share a column
    int qoff = qt * 32;

    for (int c = 0; c < 2; ++c) {               // 64-answer chunks
        __syncthreads();
        if (wm == c) {                          // 2 waves dump their quadrants
            #pragma unroll
            for (int nt = 0; nt < 4; ++nt) {
                int lcol = wn * 64 + nt * 16 + lr;
                #pragma unroll
                for (int mt = 0; mt < 4; ++mt) {
                    int lrow = mt * 16 + lg * 4;
                    scl[(lrow + 0) * 132 + lcol] = acc[mt][nt][0];
                    scl[(lrow + 1) * 132 + lcol] = acc[mt][nt][1];
                    scl[(lrow + 2) * 132 + lcol] = acc[mt][nt][2];
                    scl[(lrow + 3) * 132 + lcol] = acc[mt][nt][3];
                }
            }
        }
        __syncthreads();
        unsigned wv = bitsT[(size_t)(gt * 4 + c * 2 + qt) * BATCH + b0 + col];
        unsigned lobc = (unsigned)(127 - c * 64 - qoff);   // 127 - local base
        #pragma unroll
        for (int i = 0; i < 32; ++i) {
            float sc = scl[(qoff + i) * 132 + col];
            sc = ((wv >> i) & 1u) ? sc : 0.0f;
            unsigned key = (f2sort(sc) & 0xFFFFFF80u) | (lobc - (unsigned)i);
            t10k_ins(tp, key);
        }
    }

    // pair merge: top-10 of two sorted-desc 10-lists = {max(A[i], B[9-i])}
    unsigned q0 = __shfl_xor(tp.k0, 1), q1 = __shfl_xor(tp.k1, 1);
    unsigned q2 = __shfl_xor(tp.k2, 1), q3 = __shfl_xor(tp.k3, 1);
    unsigned q4 = __shfl_xor(tp.k4, 1), q5 = __shfl_xor(tp.k5, 1);
    unsigned q6 = __shfl_xor(tp.k6, 1), q7 = __shfl_xor(tp.k7, 1);
    unsigned q8 = __shfl_xor(tp.k8, 1), q9 = __shfl_xor(tp.k9, 1);
    if (qt == 0) {
        unsigned* dst = ck + (size_t)(b0 + col) * (NT128 * 10) + (size_t)gt * 10;
        dst[0] = umaxu(tp.k0, q9);
        dst[1] = umaxu(tp.k1, q8);
        dst[2] = umaxu(tp.k2, q7);
        dst[3] = umaxu(tp.k3, q6);
        dst[4] = umaxu(tp.k4, q5);
        dst[5] = umaxu(tp.k5, q4);
        dst[6] = umaxu(tp.k6, q3);
        dst[7] = umaxu(tp.k7, q2);
        dst[8] = umaxu(tp.k8, q1);
        dst[9] = umaxu(tp.k9, q0);
    }
}

// ---------------------------------------------------------------------------
// merge_rescore5: stream row's 10000 u32 keys (coalesced) -> per-thread
// top-16 of (key<<32)|pos -> LDS 4096 -> global top-16 -> fp64 rescore ->
// final top-10 + gather.  idx = (pos/10)*128 + 127 - (key & 0x7F).
// ---------------------------------------------------------------------------
__global__ __launch_bounds__(256) void merge_rescore5_k(
    const unsigned* __restrict__ ck,
    const float* __restrict__ P, const float* __restrict__ ANS,
    const double* __restrict__ invn64, const float* __restrict__ mask,
    float* __restrict__ out)
{
    __shared__ u64    lk[4096];
    __shared__ u64    rrk[4];
    __shared__ int    rrp[4];
    __shared__ int    topi_s[16];
    __shared__ double tops_s[16];
    __shared__ int    fin_s[10];
    int row = blockIdx.x, tid = threadIdx.x;

    Top16u t;
    t16u_init(t);
    const unsigned* ckr = ck + (size_t)row * (NT128 * 10);
    for (int j = tid; j < NT128 * 10; j += 256)
        t16u_ins(t, ((u64)ckr[j] << 32) | (unsigned)j);
    {
        int o = tid * 16;
        lk[o+0]=t.k0;  lk[o+1]=t.k1;  lk[o+2]=t.k2;  lk[o+3]=t.k3;
        lk[o+4]=t.k4;  lk[o+5]=t.k5;  lk[o+6]=t.k6;  lk[o+7]=t.k7;
        lk[o+8]=t.k8;  lk[o+9]=t.k9;  lk[o+10]=t.k10; lk[o+11]=t.k11;
        lk[o+12]=t.k12; lk[o+13]=t.k13; lk[o+14]=t.k14; lk[o+15]=t.k15;
    }
    __syncthreads();

    for (int it = 0; it < 16; ++it) {
        u64 bk = 0; int bp = -1;
        for (int j = tid; j < 4096; j += 256) {
            u64 k = lk[j];
            if (k > bk) { bk = k; bp = j; }
        }
        #pragma unroll
        for (int o = 32; o; o >>= 1) {
            u64 ok = __shfl_down(bk, o);
            int op = __shfl_down(bp, o);
            if (ok > bk) { bk = ok; bp = op; }
        }
        if ((tid & 63) == 0) { rrk[tid >> 6] = bk; rrp[tid >> 6] = bp; }
        __syncthreads();
        if (tid == 0) {
            for (int w = 1; w < 4; ++w)
                if (rrk[w] > bk) { bk = rrk[w]; bp = rrp[w]; }
            unsigned key = (unsigned)(bk >> 32);
            int pos = (int)(bk & 0xffffffffull);
            topi_s[it] = (pos / 10) * 128 + 127 - (int)(key & 0x7Fu);
            lk[bp] = 0;
        }
        __syncthreads();
    }

    // fp64 rescore: 16 threads per candidate
    int c = tid >> 4, part = tid & 15;
    int aidx = topi_s[c];
    const float4* p4 = (const float4*)(P + (size_t)row * DIM);
    const float4* a4 = (const float4*)(ANS + (size_t)aidx * DIM);
    double sum = 0.0;
    #pragma unroll
    for (int i = 0; i < 12; ++i) {
        float4 pv = p4[part * 12 + i];
        float4 av = a4[part * 12 + i];
        sum += (double)pv.x * av.x + (double)pv.y * av.y
             + (double)pv.z * av.z + (double)pv.w * av.w;
    }
    #pragma unroll
    for (int o = 8; o; o >>= 1) sum += __shfl_down(sum, o, 16);
    if (part == 0) {
        float m = mask[(size_t)row * NANS + aidx];
        tops_s[c] = sum * invn64[aidx] * (double)m;
    }
    __syncthreads();

    if (tid == 0) {
        unsigned used = 0;
        for (int k = 0; k < 10; ++k) {
            int bj = -1;
            for (int j = 0; j < 16; ++j) {
                if (used & (1u << j)) continue;
                if (bj < 0 || tops_s[j] > tops_s[bj] ||
                    (tops_s[j] == tops_s[bj] && topi_s[j] < topi_s[bj])) bj = j;
            }
            used |= 1u << bj;
            out[(size_t)row * 10 + k] = (float)tops_s[bj];
            out[10240 + (size_t)row * 10 + k] = (float)topi_s[bj];
            fin_s[k] = topi_s[bj];
        }
    }
    __syncthreads();

    for (int k = 0; k < 10; ++k) {
        int id = fin_s[k];
        const float* arow = ANS + (size_t)id * DIM;
        float* orow = out + 20480 + ((size_t)(row * 10 + k)) * DIM;
        for (int d = tid; d < DIM; d += 256) orow[d] = arow[d];
    }
}

// ---------------------------------------------------------------------------
extern "C" void kernel_launch(void* const* d_in, const int* in_sizes, int n_in,
                              void* d_out, int out_size, void* d_ws, size_t ws_size,
                              hipStream_t stream)
{
    (void)in_sizes; (void)n_in; (void)out_size;
    const float* visual = (const float*)d_in[0];
    const float* mask   = (const float*)d_in[2];
    const float* ans    = (const float*)d_in[3];
    const float* wv = (const float*)d_in[8];
    const float* bv = (const float*)d_in[9];
    const float* wo = (const float*)d_in[10];
    const float* bo = (const float*)d_in[11];
    const float* fw = (const float*)d_in[12];
    const float* fb = (const float*)d_in[13];
    const float* lg = (const float*)d_in[14];
    const float* lb = (const float*)d_in[15];
    const float* sw = (const float*)d_in[16];
    const float* sb = (const float*)d_in[17];
    float* out = (float*)d_out;

    // ---- workspace: persistent first; transient upstream + AB share tail ----
    char* w = (char*)d_ws;
    float*    P      = (float*)w;    w += (size_t)BATCH * DIM * 4;          // 3.1 MB
    short*    Pb     = (short*)w;    w += (size_t)BATCH * DIM * 2;          // 1.6 MB
    double*   invn64 = (double*)w;   w += (size_t)NANS * 8;                 // 1.0 MB
    unsigned* ck     = (unsigned*)w; w += (size_t)BATCH * NT128 * 10 * 4;   // 41 MB
    unsigned* bitsT  = (unsigned*)w; w += (size_t)NWORDS * BATCH * 4;       // 16.4 MB
    char*     tail   = w;
    float*    fused_in = (float*)tail;
    float*    v        = fused_in + (size_t)BATCH * 1536;
    float*    h        = v + (size_t)BATCH * DIM;
    short*    AB       = (short*)tail;  // reuses upstream transients after death

    size_t ab_t = (size_t)128 * DIM * 2;        // 196608 B per 128-tile
    size_t used = (size_t)(tail - (char*)d_ws);
    size_t avail = (ws_size > used) ? (ws_size - used) : ab_t;
    int CT = (int)(avail / ab_t);               // tiles per chunk
    if (CT < 1) CT = 1;
    if (CT > NT128) CT = NT128;
    int nch = (NT128 + CT - 1) / CT;

    copy_visual_k<<<512, 256, 0, stream>>>(visual, fused_in);
    gemm_bias_k<<<dim3(16, 12), 256, 0, stream>>>(visual, DIM, wv, bv, v, DIM, DIM);
    gemm_bias_k<<<dim3(16, 12), 256, 0, stream>>>(v, DIM, wo, bo, fused_in + DIM, 1536, DIM);
    gemm_bias_k<<<dim3(16, 12), 256, 0, stream>>>(fused_in, 1536, fw, fb, h, DIM, 1536);
    ln_gelu_k<<<BATCH, 256, 0, stream>>>(h, lg, lb);
    gemm_bias_k<<<dim3(16, 12), 256, 0, stream>>>(h, DIM, sw, sb, P, DIM, DIM);
    l2norm_bf_k<<<BATCH, 256, 0, stream>>>(P, Pb);
    prep_maskT_k<<<dim3(4, 200), 256, 0, stream>>>(mask, bitsT);
    // ---- upstream transients dead from here; AB reuses the tail ----

    for (int ch = 0; ch < nch; ++ch) {
        int t0 = ch * CT;
        int n = NT128 - t0; if (n > CT) n = CT;
        int nrows = n * 128;
        prep_ans_k<<<(nrows + 3) / 4, 256, 0, stream>>>(ans, t0 * 128, nrows,
                                                        invn64, AB);
        gemmsel_k<<<n * 8, 256, 0, stream>>>(Pb, AB, bitsT, ck, t0, n);
    }

    merge_rescore5_k<<<BATCH, 256, 0, stream>>>(ck, P, ans, invn64, mask, out);
}

// Round 18
// 965.915 us; speedup vs baseline: 1.0377x; 1.0313x over previous
//
#include <hip/hip_runtime.h>
#include <math.h>

#define DIM    768
#define BATCH  1024
#define NANS   128000
#define NT128  1000             // 128-answer shortlist tiles
#define NWORDS 4000             // mask bit-words per batch row (128000/32)

typedef short  bf16x8 __attribute__((ext_vector_type(8)));
typedef float  f32x4  __attribute__((ext_vector_type(4)));
typedef unsigned long long u64;

__device__ __forceinline__ short f2bf(float x)
{
    unsigned u = __builtin_bit_cast(unsigned, x);
    u += 0x7fffu + ((u >> 16) & 1u);          // RNE (no NaN inputs here)
    return (short)(u >> 16);
}

__device__ __forceinline__ void gload16(const void* g, void* l)
{
    __builtin_amdgcn_global_load_lds(
        (const __attribute__((address_space(1))) void*)g,
        (__attribute__((address_space(3))) void*)l, 16, 0, 0);
}

// sortable-u32 transform: monotone f32 -> u32 (neg -> ~u, pos -> u|0x80000000)
__device__ __forceinline__ unsigned f2sort(float s)
{
    unsigned u = __builtin_bit_cast(unsigned, s);
    return u ^ ((unsigned)((int)u >> 31) | 0x80000000u);
}

__device__ __forceinline__ unsigned umaxu(unsigned a, unsigned b) { return a > b ? a : b; }
__device__ __forceinline__ unsigned uminu(unsigned a, unsigned b) { return a < b ? a : b; }

// u32-packed top-10: key = (sortable(score) & ~0x7F) | (127 - local_idx).
// Insert = v_max_u32 + v_min_u32 per step (2 VALU) — no cndmask, no cmp.
struct Top10k { unsigned k0,k1,k2,k3,k4,k5,k6,k7,k8,k9; };
__device__ __forceinline__ void t10k_init(Top10k& t)
{ t.k0=t.k1=t.k2=t.k3=t.k4=t.k5=t.k6=t.k7=t.k8=t.k9=0u; }
__device__ __forceinline__ void t10k_ins(Top10k& t, unsigned v)
{
#define TS(K) { unsigned mx = umaxu(v, t.K); v = uminu(v, t.K); t.K = mx; }
    TS(k0) TS(k1) TS(k2) TS(k3) TS(k4) TS(k5) TS(k6) TS(k7) TS(k8) TS(k9)
#undef TS
}

// u64 top-16 for the merge phase: v = (key32<<32) | position  (10M inserts)
struct Top16u { u64 k0,k1,k2,k3,k4,k5,k6,k7,k8,k9,k10,k11,k12,k13,k14,k15; };
__device__ __forceinline__ void t16u_init(Top16u& t)
{
    t.k0=t.k1=t.k2=t.k3=t.k4=t.k5=t.k6=t.k7=0ull;
    t.k8=t.k9=t.k10=t.k11=t.k12=t.k13=t.k14=t.k15=0ull;
}
__device__ __forceinline__ void t16u_ins(Top16u& t, u64 v)
{
#define TS(K) { bool g = v > t.K; u64 mx = g ? v : t.K; v = g ? t.K : v; t.K = mx; }
    TS(k0)  TS(k1)  TS(k2)  TS(k3)  TS(k4)  TS(k5)  TS(k6)  TS(k7)
    TS(k8)  TS(k9)  TS(k10) TS(k11) TS(k12) TS(k13) TS(k14) TS(k15)
#undef TS
}

// ---------------------------------------------------------------------------
// Upstream GEMM: C[M,N] = A[M,K] @ W[N,K]^T + bias   (fp32)
// ---------------------------------------------------------------------------
__global__ __launch_bounds__(256, 2) void gemm_bias_k(
    const float* __restrict__ A, int lda,
    const float* __restrict__ W,
    const float* __restrict__ bias,
    float* __restrict__ C, int ldc, int K)
{
    __shared__ float as[32][68];
    __shared__ float bs[32][68];
    int m0 = blockIdx.x * 64, n0 = blockIdx.y * 64;
    int tid = threadIdx.x;
    int tm = tid & 15, tn = tid >> 4;
    int sr = tid >> 3, skq = tid & 7;
    float acc[4][4] = {};
    for (int k0 = 0; k0 < K; k0 += 32) {
        __syncthreads();
        #pragma unroll
        for (int p = 0; p < 2; ++p) {
            int r = sr + 32 * p;
            float4 av = *(const float4*)&A[(size_t)(m0 + r) * lda + k0 + skq * 4];
            as[skq*4+0][r] = av.x; as[skq*4+1][r] = av.y;
            as[skq*4+2][r] = av.z; as[skq*4+3][r] = av.w;
            float4 wv = *(const float4*)&W[(size_t)(n0 + r) * K + k0 + skq * 4];
            bs[skq*4+0][r] = wv.x; bs[skq*4+1][r] = wv.y;
            bs[skq*4+2][r] = wv.z; bs[skq*4+3][r] = wv.w;
        }
        __syncthreads();
        #pragma unroll 8
        for (int k = 0; k < 32; ++k) {
            float a4[4], b4[4];
            *(float4*)a4 = *(const float4*)&as[k][tm*4];
            *(float4*)b4 = *(const float4*)&bs[k][tn*4];
            #pragma unroll
            for (int i = 0; i < 4; ++i)
                #pragma unroll
                for (int j = 0; j < 4; ++j)
                    acc[i][j] = fmaf(a4[i], b4[j], acc[i][j]);
        }
    }
    float4 bv4 = *(const float4*)&bias[n0 + tn*4];
    #pragma unroll
    for (int i = 0; i < 4; ++i) {
        float4 c4;
        c4.x = acc[i][0] + bv4.x; c4.y = acc[i][1] + bv4.y;
        c4.z = acc[i][2] + bv4.z; c4.w = acc[i][3] + bv4.w;
        *(float4*)&C[(size_t)(m0 + tm*4 + i) * ldc + n0 + tn*4] = c4;
    }
}

// ---------------------------------------------------------------------------
__global__ void copy_visual_k(const float* __restrict__ src, float* __restrict__ dst)
{
    int idx = blockIdx.x * 256 + threadIdx.x;          // float4 index
    const int total = BATCH * (DIM / 4);
    for (; idx < total; idx += 512 * 256) {
        int b = idx / (DIM / 4), c = idx % (DIM / 4);
        ((float4*)dst)[(size_t)b * (1536 / 4) + c] = ((const float4*)src)[idx];
    }
}

// ---------------------------------------------------------------------------
__device__ __forceinline__ float block_sum(float v, float* red)
{
    #pragma unroll
    for (int o = 32; o; o >>= 1) v += __shfl_down(v, o);
    if ((threadIdx.x & 63) == 0) red[threadIdx.x >> 6] = v;
    __syncthreads();
    float r = red[0] + red[1] + red[2] + red[3];
    __syncthreads();
    return r;
}

__global__ __launch_bounds__(256) void ln_gelu_k(float* __restrict__ H,
        const float* __restrict__ g, const float* __restrict__ b)
{
    __shared__ float red[4];
    int row = blockIdx.x, tid = threadIdx.x;
    float* hr = H + (size_t)row * DIM;
    float v0 = hr[tid], v1 = hr[tid + 256], v2 = hr[tid + 512];
    float mu = block_sum(v0 + v1 + v2, red) * (1.0f / 768.0f);
    float d0 = v0 - mu, d1 = v1 - mu, d2 = v2 - mu;
    float var = block_sum(d0*d0 + d1*d1 + d2*d2, red) * (1.0f / 768.0f);
    float rinv = 1.0f / sqrtf(var + 1e-5f);
    #pragma unroll
    for (int q = 0; q < 3; ++q) {
        int d = tid + 256 * q;
        float dd = (q == 0 ? d0 : (q == 1 ? d1 : d2));
        float y = dd * rinv * g[d] + b[d];
        hr[d] = 0.5f * y * (1.0f + erff(y * 0.70710678118654752f));
    }
}

__global__ __launch_bounds__(256) void l2norm_bf_k(float* __restrict__ P,
        short* __restrict__ Pb)
{
    __shared__ float red[4];
    int row = blockIdx.x, tid = threadIdx.x;
    float* pr = P + (size_t)row * DIM;
    short* pb = Pb + (size_t)row * DIM;
    float v0 = pr[tid], v1 = pr[tid + 256], v2 = pr[tid + 512];
    float ss = block_sum(v0*v0 + v1*v1 + v2*v2, red);
    float inv = 1.0f / fmaxf(sqrtf(ss), 1e-12f);
    v0 *= inv; v1 *= inv; v2 *= inv;
    pr[tid] = v0; pr[tid + 256] = v1; pr[tid + 512] = v2;
    pb[tid] = f2bf(v0); pb[tid + 256] = f2bf(v1); pb[tid + 512] = f2bf(v2);
}

// ---------------------------------------------------------------------------
// prep_ans: fp64 row norm -> inv64[row]; unit-normalized bf16 rows into AB.
// ---------------------------------------------------------------------------
__global__ __launch_bounds__(256) void prep_ans_k(
    const float* __restrict__ ANS, int row0, int nrows,
    double* __restrict__ inv64, short* __restrict__ AB)
{
    int r = blockIdx.x * 4 + (threadIdx.x >> 6);
    if (r >= nrows) return;
    int row = row0 + r;
    int lane = threadIdx.x & 63;
    const float4* a4 = (const float4*)(ANS + (size_t)row * DIM);
    float4 x0 = a4[lane], x1 = a4[lane + 64], x2 = a4[lane + 128];
    double ss = (double)x0.x*x0.x + (double)x0.y*x0.y + (double)x0.z*x0.z + (double)x0.w*x0.w
              + (double)x1.x*x1.x + (double)x1.y*x1.y + (double)x1.z*x1.z + (double)x1.w*x1.w
              + (double)x2.x*x2.x + (double)x2.y*x2.y + (double)x2.z*x2.z + (double)x2.w*x2.w;
    #pragma unroll
    for (int o = 32; o; o >>= 1) ss += __shfl_xor(ss, o);
    double inv = 1.0 / fmax(sqrt(ss), 1e-12);
    if (lane == 0) inv64[row] = inv;
    float invf = (float)inv;
    short* ob = AB + (size_t)r * DIM;
    ushort4 o0, o1, o2;
    o0.x = (unsigned short)f2bf(x0.x*invf); o0.y = (unsigned short)f2bf(x0.y*invf);
    o0.z = (unsigned short)f2bf(x0.z*invf); o0.w = (unsigned short)f2bf(x0.w*invf);
    o1.x = (unsigned short)f2bf(x1.x*invf); o1.y = (unsigned short)f2bf(x1.y*invf);
    o1.z = (unsigned short)f2bf(x1.z*invf); o1.w = (unsigned short)f2bf(x1.w*invf);
    o2.x = (unsigned short)f2bf(x2.x*invf); o2.y = (unsigned short)f2bf(x2.y*invf);
    o2.z = (unsigned short)f2bf(x2.z*invf); o2.w = (unsigned short)f2bf(x2.w*invf);
    *(ushort4*)&ob[lane * 4]           = o0;
    *(ushort4*)&ob[(lane + 64) * 4]    = o1;
    *(ushort4*)&ob[(lane + 128) * 4]   = o2;
}

// ---------------------------------------------------------------------------
// prep_maskT: float mask [1024][128000] -> TRANSPOSED bits [4000][1024]
// grid (4, 100): 400 blocks x 40 words — R14-validated best (800-block
// variant measured ~30 us slower in R15/R17).
// ---------------------------------------------------------------------------
__global__ __launch_bounds__(256, 4) void prep_maskT_k(
    const float* __restrict__ mask, unsigned* __restrict__ bitsT)
{
    int r = blockIdx.x * 256 + threadIdx.x;
    int w0 = blockIdx.y * 40;
    const float* mr = mask + (size_t)r * NANS;
    for (int w = w0; w < w0 + 40; ++w) {
        const float4* p = (const float4*)(mr + w * 32);
        unsigned b = 0;
        #pragma unroll
        for (int q = 0; q < 8; ++q) {
            float4 v = p[q];
            b |= ((unsigned)(v.x != 0.f)) << (q*4+0);
            b |= ((unsigned)(v.y != 0.f)) << (q*4+1);
            b |= ((unsigned)(v.z != 0.f)) << (q*4+2);
            b |= ((unsigned)(v.w != 0.f)) << (q*4+3);
        }
        bitsT[(size_t)w * BATCH + r] = b;
    }
}

// ---------------------------------------------------------------------------
// gemmsel_k: fused MFMA GEMM (2-phase dbuf staging) + mask + per-(row,tile)
// top-10 via u32-packed max/min chains + shfl-pair bitonic merge.
// 256 thr / 4 waves; tile 128 answers x 128 batch; BK=32; 24 K-steps.
// ---------------------------------------------------------------------------
__global__ __launch_bounds__(256, 2) void gemmsel_k(
    const short* __restrict__ Pb,       // [1024][768] unit-norm bf16
    const short* __restrict__ AB,       // chunk rows, unit-norm bf16
    const unsigned* __restrict__ bitsT, // [4000][1024]
    unsigned* __restrict__ ck,          // [1024][1000*10] packed u32 keys
    int t128_0, int nt128)
{
    __shared__ __align__(16) char smem[33792];
    // staging: 2 bufs x (A [128][32] + B [128][32]) shorts
    float* scl = (float*)smem;                  // epilogue reuse: [64][132]

    int bid = blockIdx.x;
    int v = (bid & 7) * nt128 + (bid >> 3);
    int at = v >> 3, bt = v & 7;
    int gt = t128_0 + at;                       // global 128-tile id
    int a0l = at * 128, b0 = bt * 128;

    int tid = threadIdx.x;
    int lane = tid & 63, wid = tid >> 6;
    int wm = wid & 1, wn = wid >> 1;            // 2x2 wave grid of 64x64
    int lr = lane & 15, lg = lane >> 4;

    const char* gA0 = (const char*)(AB + (size_t)(a0l + (tid >> 2)) * DIM + (tid & 3) * 8);
    const char* gA1 = (const char*)(AB + (size_t)(a0l + 64 + (tid >> 2)) * DIM + (tid & 3) * 8);
    const char* gB0 = (const char*)(Pb + (size_t)(b0 + (tid >> 2)) * DIM + (tid & 3) * 8);
    const char* gB1 = (const char*)(Pb + (size_t)(b0 + 64 + (tid >> 2)) * DIM + (tid & 3) * 8);

    f32x4 acc[4][4];
    #pragma unroll
    for (int i = 0; i < 4; ++i)
        #pragma unroll
        for (int j = 0; j < 4; ++j)
            acc[i][j] = (f32x4){0.f, 0.f, 0.f, 0.f};

    // prologue: stage kt=0 into buf 0
    {
        char* la = smem + tid * 16;
        gload16(gA0, la);
        gload16(gA1, la + 4096);
        gload16(gB0, la + 16384);
        gload16(gB1, la + 20480);
    }
    __syncthreads();

    int buf = 0;
    for (int kt = 0; kt < 24; ++kt) {
        if (kt < 23) {                          // stage next tile into buf^1
            int kb = (kt + 1) * 64;
            char* la = smem + (buf ^ 1) * 8192 + tid * 16;
            gload16(gA0 + kb, la);
            gload16(gA1 + kb, la + 4096);
            gload16(gB0 + kb, la + 16384);
            gload16(gB1 + kb, la + 20480);
        }
        const short* a_sh = (const short*)(smem + buf * 8192);
        const short* b_sh = (const short*)(smem + 16384 + buf * 8192);
        bf16x8 af[4], bg[4];
        #pragma unroll
        for (int mt = 0; mt < 4; ++mt)
            af[mt] = *(const bf16x8*)(a_sh + (wm*64 + mt*16 + lr) * 32 + lg*8);
        #pragma unroll
        for (int nt = 0; nt < 4; ++nt)
            bg[nt] = *(const bf16x8*)(b_sh + (wn*64 + nt*16 + lr) * 32 + lg*8);
        #pragma unroll
        for (int mt = 0; mt < 4; ++mt)
            #pragma unroll
            for (int nt = 0; nt < 4; ++nt)
                acc[mt][nt] = __builtin_amdgcn_mfma_f32_16x16x32_bf16(
                    af[mt], bg[nt], acc[mt][nt], 0, 0, 0);
        __syncthreads();                        // drains next-tile loads too
        buf ^= 1;
    }

    // ---- epilogue: bitmask + per-column top-10, u32 keys in named regs ----
    Top10k tp;
    t10k_init(tp);
    int col = tid >> 1, qt = tid & 1;           // pair lanes share a column
    int qoff = qt * 32;

    for (int c = 0; c < 2; ++c) {               // 64-answer chunks
        __syncthreads();
        if (wm == c) {                          // 2 waves dump their quadrants
            #pragma unroll
            for (int nt = 0; nt < 4; ++nt) {
                int lcol = wn * 64 + nt * 16 + lr;
                #pragma unroll
                for (int mt = 0; mt < 4; ++mt) {
                    int lrow = mt * 16 + lg * 4;
                    scl[(lrow + 0) * 132 + lcol] = acc[mt][nt][0];
                    scl[(lrow + 1) * 132 + lcol] = acc[mt][nt][1];
                    scl[(lrow + 2) * 132 + lcol] = acc[mt][nt][2];
                    scl[(lrow + 3) * 132 + lcol] = acc[mt][nt][3];
                }
            }
        }
        __syncthreads();
        unsigned wv = bitsT[(size_t)(gt * 4 + c * 2 + qt) * BATCH + b0 + col];
        unsigned lobc = (unsigned)(127 - c * 64 - qoff);   // 127 - local base
        #pragma unroll
        for (int i = 0; i < 32; ++i) {
            float sc = scl[(qoff + i) * 132 + col];
            sc = ((wv >> i) & 1u) ? sc : 0.0f;
            unsigned key = (f2sort(sc) & 0xFFFFFF80u) | (lobc - (unsigned)i);
            t10k_ins(tp, key);
        }
    }

    // pair merge: top-10 of two sorted-desc 10-lists = {max(A[i], B[9-i])}
    unsigned q0 = __shfl_xor(tp.k0, 1), q1 = __shfl_xor(tp.k1, 1);
    unsigned q2 = __shfl_xor(tp.k2, 1), q3 = __shfl_xor(tp.k3, 1);
    unsigned q4 = __shfl_xor(tp.k4, 1), q5 = __shfl_xor(tp.k5, 1);
    unsigned q6 = __shfl_xor(tp.k6, 1), q7 = __shfl_xor(tp.k7, 1);
    unsigned q8 = __shfl_xor(tp.k8, 1), q9 = __shfl_xor(tp.k9, 1);
    if (qt == 0) {
        unsigned* dst = ck + (size_t)(b0 + col) * (NT128 * 10) + (size_t)gt * 10;
        dst[0] = umaxu(tp.k0, q9);
        dst[1] = umaxu(tp.k1, q8);
        dst[2] = umaxu(tp.k2, q7);
        dst[3] = umaxu(tp.k3, q6);
        dst[4] = umaxu(tp.k4, q5);
        dst[5] = umaxu(tp.k5, q4);
        dst[6] = umaxu(tp.k6, q3);
        dst[7] = umaxu(tp.k7, q2);
        dst[8] = umaxu(tp.k8, q1);
        dst[9] = umaxu(tp.k9, q0);
    }
}

// ---------------------------------------------------------------------------
// merge_rescore5: stream row's 10000 u32 keys (coalesced) -> per-thread
// top-16 of (key<<32)|pos -> LDS 4096 -> global top-16 -> fp64 rescore ->
// final top-10 + gather.  idx = (pos/10)*128 + 127 - (key & 0x7F).
// ---------------------------------------------------------------------------
__global__ __launch_bounds__(256) void merge_rescore5_k(
    const unsigned* __restrict__ ck,
    const float* __restrict__ P, const float* __restrict__ ANS,
    const double* __restrict__ invn64, const float* __restrict__ mask,
    float* __restrict__ out)
{
    __shared__ u64    lk[4096];
    __shared__ u64    rrk[4];
    __shared__ int    rrp[4];
    __shared__ int    topi_s[16];
    __shared__ double tops_s[16];
    __shared__ int    fin_s[10];
    int row = blockIdx.x, tid = threadIdx.x;

    Top16u t;
    t16u_init(t);
    const unsigned* ckr = ck + (size_t)row * (NT128 * 10);
    for (int j = tid; j < NT128 * 10; j += 256)
        t16u_ins(t, ((u64)ckr[j] << 32) | (unsigned)j);
    {
        int o = tid * 16;
        lk[o+0]=t.k0;  lk[o+1]=t.k1;  lk[o+2]=t.k2;  lk[o+3]=t.k3;
        lk[o+4]=t.k4;  lk[o+5]=t.k5;  lk[o+6]=t.k6;  lk[o+7]=t.k7;
        lk[o+8]=t.k8;  lk[o+9]=t.k9;  lk[o+10]=t.k10; lk[o+11]=t.k11;
        lk[o+12]=t.k12; lk[o+13]=t.k13; lk[o+14]=t.k14; lk[o+15]=t.k15;
    }
    __syncthreads();

    for (int it = 0; it < 16; ++it) {
        u64 bk = 0; int bp = -1;
        for (int j = tid; j < 4096; j += 256) {
            u64 k = lk[j];
            if (k > bk) { bk = k; bp = j; }
        }
        #pragma unroll
        for (int o = 32; o; o >>= 1) {
            u64 ok = __shfl_down(bk, o);
            int op = __shfl_down(bp, o);
            if (ok > bk) { bk = ok; bp = op; }
        }
        if ((tid & 63) == 0) { rrk[tid >> 6] = bk; rrp[tid >> 6] = bp; }
        __syncthreads();
        if (tid == 0) {
            for (int w = 1; w < 4; ++w)
                if (rrk[w] > bk) { bk = rrk[w]; bp = rrp[w]; }
            unsigned key = (unsigned)(bk >> 32);
            int pos = (int)(bk & 0xffffffffull);
            topi_s[it] = (pos / 10) * 128 + 127 - (int)(key & 0x7Fu);
            lk[bp] = 0;
        }
        __syncthreads();
    }

    // fp64 rescore: 16 threads per candidate
    int c = tid >> 4, part = tid & 15;
    int aidx = topi_s[c];
    const float4* p4 = (const float4*)(P + (size_t)row * DIM);
    const float4* a4 = (const float4*)(ANS + (size_t)aidx * DIM);
    double sum = 0.0;
    #pragma unroll
    for (int i = 0; i < 12; ++i) {
        float4 pv = p4[part * 12 + i];
        float4 av = a4[part * 12 + i];
        sum += (double)pv.x * av.x + (double)pv.y * av.y
             + (double)pv.z * av.z + (double)pv.w * av.w;
    }
    #pragma unroll
    for (int o = 8; o; o >>= 1) sum += __shfl_down(sum, o, 16);
    if (part == 0) {
        float m = mask[(size_t)row * NANS + aidx];
        tops_s[c] = sum * invn64[aidx] * (double)m;
    }
    __syncthreads();

    if (tid == 0) {
        unsigned used = 0;
        for (int k = 0; k < 10; ++k) {
            int bj = -1;
            for (int j = 0; j < 16; ++j) {
                if (used & (1u << j)) continue;
                if (bj < 0 || tops_s[j] > tops_s[bj] ||
                    (tops_s[j] == tops_s[bj] && topi_s[j] < topi_s[bj])) bj = j;
            }
            used |= 1u << bj;
            out[(size_t)row * 10 + k] = (float)tops_s[bj];
            out[10240 + (size_t)row * 10 + k] = (float)topi_s[bj];
            fin_s[k] = topi_s[bj];
        }
    }
    __syncthreads();

    for (int k = 0; k < 10; ++k) {
        int id = fin_s[k];
        const float* arow = ANS + (size_t)id * DIM;
        float* orow = out + 20480 + ((size_t)(row * 10 + k)) * DIM;
        for (int d = tid; d < DIM; d += 256) orow[d] = arow[d];
    }
}

// ---------------------------------------------------------------------------
extern "C" void kernel_launch(void* const* d_in, const int* in_sizes, int n_in,
                              void* d_out, int out_size, void* d_ws, size_t ws_size,
                              hipStream_t stream)
{
    (void)in_sizes; (void)n_in; (void)out_size;
    const float* visual = (const float*)d_in[0];
    const float* mask   = (const float*)d_in[2];
    const float* ans    = (const float*)d_in[3];
    const float* wv = (const float*)d_in[8];
    const float* bv = (const float*)d_in[9];
    const float* wo = (const float*)d_in[10];
    const float* bo = (const float*)d_in[11];
    const float* fw = (const float*)d_in[12];
    const float* fb = (const float*)d_in[13];
    const float* lg = (const float*)d_in[14];
    const float* lb = (const float*)d_in[15];
    const float* sw = (const float*)d_in[16];
    const float* sb = (const float*)d_in[17];
    float* out = (float*)d_out;

    // ---- workspace: persistent first; transient upstream + AB share tail ----
    char* w = (char*)d_ws;
    float*    P      = (float*)w;    w += (size_t)BATCH * DIM * 4;          // 3.1 MB
    short*    Pb     = (short*)w;    w += (size_t)BATCH * DIM * 2;          // 1.6 MB
    double*   invn64 = (double*)w;   w += (size_t)NANS * 8;                 // 1.0 MB
    unsigned* ck     = (unsigned*)w; w += (size_t)BATCH * NT128 * 10 * 4;   // 41 MB
    unsigned* bitsT  = (unsigned*)w; w += (size_t)NWORDS * BATCH * 4;       // 16.4 MB
    char*     tail   = w;
    float*    fused_in = (float*)tail;
    float*    v        = fused_in + (size_t)BATCH * 1536;
    float*    h        = v + (size_t)BATCH * DIM;
    short*    AB       = (short*)tail;  // reuses upstream transients after death

    size_t ab_t = (size_t)128 * DIM * 2;        // 196608 B per 128-tile
    size_t used = (size_t)(tail - (char*)d_ws);
    size_t avail = (ws_size > used) ? (ws_size - used) : ab_t;
    int CT = (int)(avail / ab_t);               // tiles per chunk
    if (CT < 1) CT = 1;
    if (CT > NT128) CT = NT128;
    int nch = (NT128 + CT - 1) / CT;

    copy_visual_k<<<512, 256, 0, stream>>>(visual, fused_in);
    gemm_bias_k<<<dim3(16, 12), 256, 0, stream>>>(visual, DIM, wv, bv, v, DIM, DIM);
    gemm_bias_k<<<dim3(16, 12), 256, 0, stream>>>(v, DIM, wo, bo, fused_in + DIM, 1536, DIM);
    gemm_bias_k<<<dim3(16, 12), 256, 0, stream>>>(fused_in, 1536, fw, fb, h, DIM, 1536);
    ln_gelu_k<<<BATCH, 256, 0, stream>>>(h, lg, lb);
    gemm_bias_k<<<dim3(16, 12), 256, 0, stream>>>(h, DIM, sw, sb, P, DIM, DIM);
    l2norm_bf_k<<<BATCH, 256, 0, stream>>>(P, Pb);
    prep_maskT_k<<<dim3(4, 100), 256, 0, stream>>>(mask, bitsT);
    // ---- upstream transients dead from here; AB reuses the tail ----

    for (int ch = 0; ch < nch; ++ch) {
        int t0 = ch * CT;
        int n = NT128 - t0; if (n > CT) n = CT;
        int nrows = n * 128;
        prep_ans_k<<<(nrows + 3) / 4, 256, 0, stream>>>(ans, t0 * 128, nrows,
                                                        invn64, AB);
        gemmsel_k<<<n * 8, 256, 0, stream>>>(Pb, AB, bitsT, ck, t0, n);
    }

    merge_rescore5_k<<<BATCH, 256, 0, stream>>>(ck, P, ans, invn64, mask, out);
}